// Round 8
// baseline (529.206 us; speedup 1.0000x reference)
//
#include <hip/hip_runtime.h>
#include <cmath>

#define B_ 1024
#define CIN_ 22
#define T1_ 438
#define COUT_ 20
#define T2_ 439

// ws float offsets
#define OFF_S 0
#define OFF_M 32
#define OFF_SUM2 576
#define OFF_SSQ2 608
#define OFF_A2 640
#define OFF_ACC_END 704
#define OFF_C 1024
#define OFF_LQ (OFF_C + B_*3*400)
#define OFF_LK (OFF_LQ + B_*3*324)
#define OFF_LV (OFF_LK + B_*3*324)
#define OFF_WEFF (OFF_LV + B_*3*324)
#define OFF_BPRE (OFF_WEFF + 5280)

__global__ __launch_bounds__(256) void k_zero(float* ws){
  for(int i=threadIdx.x; i<OFF_ACC_END; i+=256) ws[i]=0.f;
}

// bn1 stats via second-moment matrix of x: S[22], M[22][22] (triu), float4 dots
__global__ __launch_bounds__(256) void k_moment(const float* __restrict__ x, float* __restrict__ ws){
  __shared__ float xs[CIN_][440];
  int b=blockIdx.x;
  const float* xb = x + (size_t)b*CIN_*T1_;
  for(int i=threadIdx.x;i<CIN_*T1_;i+=256){
    int h=i/T1_, t=i-h*T1_;
    xs[h][t]=xb[i];
  }
  if(threadIdx.x<CIN_){ xs[threadIdx.x][438]=0.f; xs[threadIdx.x][439]=0.f; }
  __syncthreads();
  for(int tgt=threadIdx.x; tgt<275; tgt+=256){
    if(tgt<253){
      int r=tgt, i=0;
      while(true){ int c=CIN_-i; if(r<c) break; r-=c; i++; }
      int j=i+r;
      const float4* ri=(const float4*)&xs[i][0];
      const float4* rj=(const float4*)&xs[j][0];
      float acc=0.f;
      for(int t=0;t<110;t++){
        float4 a=ri[t], bb=rj[t];
        acc += a.x*bb.x + a.y*bb.y + a.z*bb.z + a.w*bb.w;
      }
      atomicAdd(&ws[OFF_M + i*CIN_ + j], acc);
    } else {
      int c=tgt-253;
      const float4* rc=(const float4*)&xs[c][0];
      float acc=0.f;
      for(int t=0;t<110;t++){
        float4 a=rc[t];
        acc += a.x + a.y + a.z + a.w;
      }
      atomicAdd(&ws[OFF_S + c], acc);
    }
  }
}

// bn1 closed-form + fold conv1/bn1 into conv2: Weff[o][h][k], bias prefix pre[o][13]
__global__ __launch_bounds__(256) void k_prep(const float* __restrict__ w1, const float* __restrict__ cb1,
                                              const float* __restrict__ g1, const float* __restrict__ bb1,
                                              const float* __restrict__ w2, float* __restrict__ ws){
  __shared__ float a1s[CIN_], e1s[CIN_];
  int tid=threadIdx.x;
  if(tid<CIN_){
    int c=tid;
    const double N = (double)B_*T1_;
    double wS=0.0, wMw=0.0;
    for(int h=0;h<CIN_;h++) wS += (double)w1[c*CIN_+h]*(double)ws[OFF_S+h];
    for(int h=0;h<CIN_;h++){
      for(int h2=0;h2<CIN_;h2++){
        int i=h<h2?h:h2, j=h<h2?h2:h;
        wMw += (double)w1[c*CIN_+h]*(double)w1[c*CIN_+h2]*(double)ws[OFF_M+i*CIN_+j];
      }
    }
    double bc=cb1[c];
    double mean=wS/N+bc;
    double ex2=(wMw+2.0*bc*wS)/N+bc*bc;
    double var=ex2-mean*mean;
    double a1=(double)g1[c]/sqrt(var+1e-5);
    double d1=(double)bb1[c]-mean*a1;
    a1s[c]=(float)a1;
    e1s[c]=(float)(a1*bc+d1);
  }
  __syncthreads();
  for(int idx=tid; idx<5280; idx+=256){
    int o=idx/264, r=idx-o*264, h=r/12, k=r-h*12;
    float s=0.f;
    for(int i=0;i<CIN_;i++) s += w2[(o*CIN_+i)*12+k]*a1s[i]*w1[i*CIN_+h];
    ws[OFF_WEFF+idx]=s;
  }
  if(tid<COUT_){
    float pre=0.f;
    ws[OFF_BPRE+tid*13+0]=0.f;
    for(int k=0;k<12;k++){
      float wb=0.f;
      for(int i=0;i<CIN_;i++) wb += w2[(tid*CIN_+i)*12+k]*e1s[i];
      pre += wb;
      ws[OFF_BPRE+tid*13+k+1]=pre;
    }
  }
}

// direct conv x->h2 (folded kernel) + per-patch covariance + bn2 sums.
__global__ __launch_bounds__(256) void k_cov(const float* __restrict__ x,
                                             float* __restrict__ ws){
  __shared__ float Wl[5280];
  __shared__ float preL[COUT_][13];
  __shared__ float xs[CIN_][168];
  __shared__ float h2w[COUT_][156];
  __shared__ float pmu[COUT_];
  int b=blockIdx.x, tid=threadIdx.x;
  for(int i=tid;i<5280;i+=256) Wl[i]=ws[OFF_WEFF+i];
  for(int i=tid;i<260;i+=256) ((float*)preL)[i]=ws[OFF_BPRE+i];
  int pi=0,pj=0;
  if(tid<210){ int r=tid,i=0; while(true){int c=COUT_-i; if(r<c)break; r-=c; i++;} pi=i; pj=i+r; }
  int sc = tid-210;
  float ac1=0.f, ac2=0.f;
  const float* xb = x + (size_t)b*CIN_*T1_;
  int o = tid/12, cch = tid-12*o;
  int t0 = cch*13;
  for(int p=0;p<3;p++){
    const int off = (p==0)?0:((p==1)?147:293);
    const int L = (p==0)?147:146;
    __syncthreads();
    for(int idx=tid; idx<CIN_*168; idx+=256){
      int h=idx/168, c2=idx-h*168;
      int gxt = off-6+c2;
      xs[h][c2] = (c2<167 && gxt>=0 && gxt<T1_) ? xb[h*T1_+gxt] : 0.f;
    }
    __syncthreads();
    if(tid<240){
      float acc[13];
      #pragma unroll
      for(int j=0;j<13;j++){
        int gt = off+t0+j;
        int kmin = 6-gt; kmin = kmin<0?0:kmin;
        int kmax = 443-gt; kmax = kmax>11?11:kmax;
        acc[j] = (kmax>=kmin)? preL[o][kmax+1]-preL[o][kmin] : 0.f;
      }
      const float* Wo = &Wl[o*264];
      for(int h=0;h<CIN_;h++){
        float xw[24];
        #pragma unroll
        for(int c2=0;c2<24;c2++) xw[c2]=xs[h][t0+c2];
        const float* Wh = Wo + h*12;
        #pragma unroll
        for(int k=0;k<12;k++){
          float w=Wh[k];
          #pragma unroll
          for(int j=0;j<13;j++) acc[j] += w*xw[j+k];
        }
      }
      #pragma unroll
      for(int j=0;j<13;j++) if(t0+j<L) h2w[o][t0+j]=acc[j];
    } else {
      int npad = 156-L;
      for(int z=tid-240; z<COUT_*npad; z+=16){
        int oo=z/npad, c2=z-oo*npad;
        h2w[oo][L+c2]=0.f;
      }
    }
    __syncthreads();
    float s=0.f;
    if(tid<210){
      const float4* ri=(const float4*)&h2w[pi][0];
      const float4* rj=(const float4*)&h2w[pj][0];
      for(int t=0;t<39;t++){
        float4 a=ri[t], bb=rj[t];
        s += a.x*bb.x + a.y*bb.y + a.z*bb.z + a.w*bb.w;
      }
    } else if(sc>=0 && sc<COUT_){
      const float4* rc=(const float4*)&h2w[sc][0];
      float s1=0.f,s2=0.f;
      for(int t=0;t<39;t++){
        float4 a=rc[t];
        s1 += a.x+a.y+a.z+a.w;
        s2 += a.x*a.x+a.y*a.y+a.z*a.z+a.w*a.w;
      }
      ac1+=s1; ac2+=s2; pmu[sc]=s1/(float)L;
    }
    __syncthreads();
    if(tid<210){
      s -= (float)L*pmu[pi]*pmu[pj];
      float* Cb = ws + OFF_C + ((size_t)b*3+p)*400;
      Cb[pi*COUT_+pj]=s; Cb[pj*COUT_+pi]=s;
    }
  }
  if(sc>=0 && sc<COUT_){
    atomicAdd(&ws[OFF_SUM2+sc], ac1);
    atomicAdd(&ws[OFF_SSQ2+sc], ac2);
  }
}

__global__ void k_fin2(const float* __restrict__ g2, float* __restrict__ ws){
  int c=threadIdx.x; if(c>=COUT_) return;
  const double N=(double)B_*T2_;
  double m=ws[OFF_SUM2+c]/N;
  double v=ws[OFF_SSQ2+c]/N - m*m;
  ws[OFF_A2+c]=(float)((double)g2[c]/sqrt(v+1e-5));
}

// ---------------------------------------------------------------------------
// Brent-Luk one-sided Jacobi for SPD 18x18, columns-in-lanes (see R5-R7 notes).
// 9 lanes per matrix. V-free: converged cols = lambda*u. Exit 3e-3 (applied-
// sweep residual ~ smax^2).
// ---------------------------------------------------------------------------
__device__ __forceinline__ void bl_jacobi(float P[18], float Q[18],
                                          float &dgp, float &dgq,
                                          int l9, int srcP, int srcQ, int maxsweep){
  for(int sweep=0; sweep<maxsweep; sweep++){
    float n0=0.f,n1=0.f,m0=0.f,m1=0.f;
    #pragma unroll
    for(int k=0;k<18;k+=2){
      n0 += P[k]*P[k];   n1 += P[k+1]*P[k+1];
      m0 += Q[k]*Q[k];   m1 += Q[k+1]*Q[k+1];
    }
    dgp = n0+n1; dgq = m0+m1;
    float smax = 0.f;
    for(int r=0;r<17;r++){
      float a0=0.f,a1=0.f;
      #pragma unroll
      for(int k=0;k<18;k+=2){ a0 += P[k]*Q[k]; a1 += P[k+1]*Q[k+1]; }
      float apq = a0+a1;
      float tau = __fdividef(dgq-dgp, 2.f*apq);
      float tt  = __fdividef(copysignf(1.f,tau), fabsf(tau)+sqrtf(1.f+tau*tau));
      float c   = rsqrtf(1.f+tt*tt);
      float s   = tt*c;
      bool  z   = (apq==0.f);
      tt = z?0.f:tt; c = z?1.f:c; s = z?0.f:s;
      float ndgp = dgp - tt*apq;
      float ndgq = dgq + tt*apq;
      smax = fmaxf(smax, fabsf(s));
      #pragma unroll
      for(int k=0;k<18;k++){
        float x=P[k], y=Q[k];
        float rp = c*x - s*y;
        float rq = s*x + c*y;
        float np = __shfl(rp, srcP);
        np = (l9==8) ? rq : np;
        float sq = (l9==0) ? rp : rq;
        float nq = __shfl(sq, srcQ);
        P[k] = np;
        Q[k] = (l9==0) ? rq : nq;
      }
      {
        float np = __shfl(ndgp, srcP);
        np = (l9==8) ? ndgq : np;
        float sq = (l9==0) ? ndgp : ndgq;
        float nq = __shfl(sq, srcQ);
        dgp = np;
        dgq = (l9==0) ? ndgq : nq;
      }
    }
    if(__all(smax < 3e-3f)) break;
  }
  float n0=0.f,n1=0.f,m0=0.f,m1=0.f;
  #pragma unroll
  for(int k=0;k<18;k+=2){
    n0 += P[k]*P[k];   n1 += P[k+1]*P[k+1];
    m0 += Q[k]*Q[k];   m1 += Q[k+1]*Q[k+1];
  }
  dgp = n0+n1; dgq = m0+m1;
}

// One (b,p) per 1-wave block: stage C once, three congruences (Wa=W*a2, W^TW=I
// so 1/tr and +1e-5I fold into spectral weights), 3 Jacobi groups (27 lanes),
// logm -> LQ/LK/LV. 3072 blocks = 3 waves/SIMD; ~11.6KB LDS (Mc aliases Wa).
__global__ __launch_bounds__(64) void k_eigh3(const float* __restrict__ Wq,
                                              const float* __restrict__ Wk,
                                              const float* __restrict__ Wv,
                                              float* __restrict__ ws){
  __shared__ float S[2905];
  float* Wa  = S;          // 1080 (3x360); aliased as Mc after Jacobi
  float* a2s = S+1080;     // 20
  float* Cs  = S+1100;     // 400 raw C
  float* Tt  = S+1500;     // 378 (18x21)
  float* ob  = S+1878;     // 972: Af x3, then out staging
  float* gl  = S+2850;     // 54
  float* trp = S+2904;     // 1
  int bp=blockIdx.x, tid=threadIdx.x;
  if(tid<20) a2s[tid]=ws[OFF_A2+tid];
  __syncthreads();
  for(int i=tid;i<1080;i+=64){
    int m=i/360, r=i-m*360, row=r/18;
    const float* W = (m==0)?Wq:((m==1)?Wk:Wv);
    Wa[i] = W[r]*a2s[row];
  }
  const float* Cb = ws + OFF_C + (size_t)bp*400;
  for(int i=tid;i<400;i+=64) Cs[i]=Cb[i];
  __syncthreads();
  if(tid==0){
    float tr=0.f;
    #pragma unroll
    for(int i=0;i<20;i++) tr += Cs[i*20+i]*a2s[i]*a2s[i];
    trp[0]=tr;
  }
  __syncthreads();
  float tr = trp[0];
  float sh = 1e-5f*tr;
  float logtr = logf(tr);
  // 3 congruences: B_m = Wa_m^T C Wa_m (plain; scaling folded into weights)
  for(int m=0;m<3;m++){
    const float* Wm = Wa + m*360;
    for(int idx=tid; idx<360; idx+=64){
      int a=idx/20, j=idx-a*20;
      float s=0.f;
      for(int i=0;i<20;i++) s += Wm[i*18+a]*Cs[i*20+j];
      Tt[a*21+j]=s;
    }
    __syncthreads();
    for(int idx=tid; idx<324; idx+=64){
      int a=idx/18, c=idx-a*18;
      float s=0.f;
      for(int j=0;j<20;j++) s += Tt[a*21+j]*Wm[j*18+c];
      ob[m*324+idx]=s;
    }
    __syncthreads();
  }
  int g=tid/9, l9=tid-9*g;
  int srcP=min(g*9+((l9==8)?8:(l9+1)),63);
  int srcQ=g*9+((l9==0)?0:(l9-1));
  int ps=l9, qs=(l9==0)?17:(17-l9);
  float P[18],Q[18],dgp,dgq;
  if(g<3){
    const float* Ag = ob+g*324;
    #pragma unroll
    for(int k=0;k<18;k++){
      P[k]=0.5f*(Ag[k*18+ps]+Ag[ps*18+k]) + ((k==ps)?sh:0.f);
      Q[k]=0.5f*(Ag[k*18+qs]+Ag[qs*18+k]) + ((k==qs)?sh:0.f);
    }
  } else {
    #pragma unroll
    for(int k=0;k<18;k++){ P[k]=0.f; Q[k]=0.f; }
  }
  __syncthreads();
  bl_jacobi(P,Q,dgp,dgq,l9,srcP,srcQ,8);
  // lambda_true = sqrt(dg)/tr; g_k = log(lambda_true)/dg = (0.5*log(dg)-log(tr))/dg
  float dp = fmaxf(dgp,1e-30f), dq = fmaxf(dgq,1e-30f);
  float gpv = __fdividef(0.5f*logf(dp)-logtr, dp);
  float gqv = __fdividef(0.5f*logf(dq)-logtr, dq);
  float* Mc = Wa;  // Wa dead
  if(g<3){
    #pragma unroll
    for(int k=0;k<18;k++){
      Mc[g*360 + k*20 + ps]=P[k];
      Mc[g*360 + k*20 + qs]=Q[k];
    }
    gl[g*18+ps]=gpv; gl[g*18+qs]=gqv;
  }
  __syncthreads();
  // out rows: 3 mats x 18 rows = 54 (single pass)
  if(tid<54){
    int mat=tid/18, i=tid-mat*18;
    float w[18];
    #pragma unroll
    for(int k=0;k<18;k++) w[k]=gl[mat*18+k]*Mc[mat*360+i*20+k];
    for(int j=0;j<18;j++){
      float s=0.f;
      #pragma unroll
      for(int k=0;k<18;k++) s += w[k]*Mc[mat*360+j*20+k];
      ob[mat*324+i*18+j]=s;
    }
  }
  __syncthreads();
  const float4* s4=(const float4*)ob;
  for(int i=tid;i<243;i+=64){
    int mat=i/81, r=i-mat*81;
    float4* dst=(float4*)(ws + ((mat==0)?OFF_LQ:((mat==1)?OFF_LK:OFF_LV)) + (size_t)bp*324);
    dst[r]=s4[i];
  }
}

// fused: energies + softmax + mean_log + eigh(+12I) + triu feat + LINEAR out
__global__ __launch_bounds__(64) void k_att2(const float* __restrict__ lw,
                                             const float* __restrict__ lb,
                                             float* __restrict__ ws,
                                             float* __restrict__ out){
  __shared__ float lv[972];     // aliased as feat (513) after ml computed
  __shared__ float lqk[1944];   // lq | lk ; reused as ml after softmax
  __shared__ float e9[9];
  __shared__ float prob[9];
  __shared__ float Mc[1080];
  __shared__ float gl[54];
  int b=blockIdx.x, tid=threadIdx.x;
  const float4* LQ4=(const float4*)(ws+OFF_LQ+(size_t)b*972);
  const float4* LK4=(const float4*)(ws+OFF_LK+(size_t)b*972);
  const float4* LV4=(const float4*)(ws+OFF_LV+(size_t)b*972);
  float4* lqk4=(float4*)lqk; float4* lv4=(float4*)lv;
  for(int i=tid;i<243;i+=64){ lqk4[i]=LQ4[i]; lqk4[243+i]=LK4[i]; lv4[i]=LV4[i]; }
  __syncthreads();
  if(tid<36){
    int d=tid>>2, sub=tid&3;
    int ii=d/3, p=d-ii*3;
    const float* kk=lqk+972+ii*324+sub*81;
    const float* qq=lqk+p*324+sub*81;
    float s=0.f;
    for(int el=0;el<81;el++){ float dd=kk[el]-qq[el]; s+=dd*dd; }
    s += __shfl_xor(s,1); s += __shfl_xor(s,2);
    if(sub==0) e9[d]=s;
  }
  __syncthreads();
  if(tid<3){
    int p=tid;
    float f0=1.f/(1.f+log1pf(e9[0+p]));
    float f1=1.f/(1.f+log1pf(e9[3+p]));
    float f2=1.f/(1.f+log1pf(e9[6+p]));
    float mx=fmaxf(f0,fmaxf(f1,f2));
    float x0=expf(f0-mx), x1=expf(f1-mx), x2=expf(f2-mx);
    float inv=1.f/(x0+x1+x2);
    prob[p*3+0]=x0*inv; prob[p*3+1]=x1*inv; prob[p*3+2]=x2*inv;
  }
  __syncthreads();
  float* ml = lqk;
  for(int idx=tid; idx<972; idx+=64){
    int p=idx/324, el=idx-p*324;
    ml[idx]=prob[p*3+0]*lv[el]+prob[p*3+1]*lv[324+el]+prob[p*3+2]*lv[648+el];
  }
  __syncthreads();
  int g=tid/9, l9=tid-9*g;
  int srcP=min(g*9+((l9==8)?8:(l9+1)),63);
  int srcQ=g*9+((l9==0)?0:(l9-1));
  int ps=l9, qs=(l9==0)?17:(17-l9);
  float P[18],Q[18],dgp,dgq;
  if(g<3){
    const float* Ag=ml+g*324;
    #pragma unroll
    for(int k=0;k<18;k++){
      P[k]=0.5f*(Ag[k*18+ps]+Ag[ps*18+k]) + ((k==ps)?12.f:0.f);
      Q[k]=0.5f*(Ag[k*18+qs]+Ag[qs*18+k]) + ((k==qs)?12.f:0.f);
    }
  } else {
    #pragma unroll
    for(int k=0;k<18;k++){ P[k]=0.f; Q[k]=0.f; }
  }
  __syncthreads();
  bl_jacobi(P,Q,dgp,dgq,l9,srcP,srcQ,8);
  float lp=sqrtf(dgp), lqv=sqrtf(dgq);
  float gpv=__fdividef(fmaxf(lp-12.f,-9.2103404f), fmaxf(dgp,1e-12f));
  float gqv=__fdividef(fmaxf(lqv-12.f,-9.2103404f), fmaxf(dgq,1e-12f));
  if(g<3){
    #pragma unroll
    for(int k=0;k<18;k++){
      Mc[g*360 + k*20 + ps]=P[k];
      Mc[g*360 + k*20 + qs]=Q[k];
    }
    gl[g*18+ps]=gpv; gl[g*18+qs]=gqv;
  }
  __syncthreads();
  // triu(tang) -> feat (LDS, aliases lv which is dead)
  float* feat = lv;
  if(tid<54){
    int mat=tid/18, i=tid-mat*18;
    float w[18];
    #pragma unroll
    for(int k=0;k<18;k++) w[k]=gl[mat*18+k]*Mc[mat*360+i*20+k];
    int base = mat*171 + (i*18 - (i*(i-1))/2) - i;
    for(int j=i;j<18;j++){
      float s=0.f;
      #pragma unroll
      for(int k=0;k<18;k++) s += w[k]*Mc[mat*360+j*20+k];
      feat[base+j]=s;
    }
  }
  __syncthreads();
  // linear: out[b][j] = lb[j] + dot(feat, lw[j]); 16 lanes per output
  int j4 = tid&3, chunk = tid>>2;
  float s=0.f;
  const float* wj = lw + j4*513;
  for(int k=chunk; k<513; k+=16) s += feat[k]*wj[k];
  s += __shfl_xor(s,4); s += __shfl_xor(s,8);
  s += __shfl_xor(s,16); s += __shfl_xor(s,32);
  if(chunk==0) out[b*4+j4] = s + lb[j4];
}

extern "C" void kernel_launch(void* const* d_in, const int* in_sizes, int n_in,
                              void* d_out, int out_size, void* d_ws, size_t ws_size,
                              hipStream_t stream){
  const float* x  =(const float*)d_in[0];
  const float* w1 =(const float*)d_in[1];
  const float* cb1=(const float*)d_in[2];
  const float* g1 =(const float*)d_in[3];
  const float* bb1=(const float*)d_in[4];
  const float* w2 =(const float*)d_in[5];
  // d_in[6] conv2_b, d_in[8] bn2_b: provably cancel
  const float* g2 =(const float*)d_in[7];
  const float* Wq =(const float*)d_in[9];
  const float* Wk =(const float*)d_in[10];
  const float* Wv =(const float*)d_in[11];
  const float* lw =(const float*)d_in[12];
  const float* lb =(const float*)d_in[13];
  float* ws=(float*)d_ws;
  float* out=(float*)d_out;

  k_zero<<<1,256,0,stream>>>(ws);
  k_moment<<<B_,256,0,stream>>>(x,ws);
  k_prep<<<1,256,0,stream>>>(w1,cb1,g1,bb1,w2,ws);
  k_cov<<<B_,256,0,stream>>>(x,ws);
  k_fin2<<<1,64,0,stream>>>(g2,ws);
  k_eigh3<<<3072,64,0,stream>>>(Wq,Wk,Wv,ws);   // one (b,p) per wave
  k_att2<<<B_,64,0,stream>>>(lw,lb,ws,out);     // fused att+eigh2+feat+linear
}

// Round 9
// 465.942 us; speedup vs baseline: 1.1358x; 1.1358x over previous
//
#include <hip/hip_runtime.h>
#include <cmath>

#define B_ 1024
#define CIN_ 22
#define T1_ 438
#define COUT_ 20
#define T2_ 439

// ws float offsets
#define OFF_S 0
#define OFF_M 32
#define OFF_SUM2 576
#define OFF_SSQ2 608
#define OFF_A2 640
#define OFF_ACC_END 704
#define OFF_C 1024
#define OFF_LQ (OFF_C + B_*3*400)
#define OFF_LK (OFF_LQ + B_*3*324)
#define OFF_LV (OFF_LK + B_*3*324)
#define OFF_WEFF (OFF_LV + B_*3*324)
#define OFF_BPRE (OFF_WEFF + 5280)

__global__ __launch_bounds__(256) void k_zero(float* ws){
  for(int i=threadIdx.x; i<OFF_ACC_END; i+=256) ws[i]=0.f;
}

// bn1 stats via second-moment matrix of x: S[22], M[22][22] (triu), float4 dots
__global__ __launch_bounds__(256) void k_moment(const float* __restrict__ x, float* __restrict__ ws){
  __shared__ float xs[CIN_][440];
  int b=blockIdx.x;
  const float* xb = x + (size_t)b*CIN_*T1_;
  for(int i=threadIdx.x;i<CIN_*T1_;i+=256){
    int h=i/T1_, t=i-h*T1_;
    xs[h][t]=xb[i];
  }
  if(threadIdx.x<CIN_){ xs[threadIdx.x][438]=0.f; xs[threadIdx.x][439]=0.f; }
  __syncthreads();
  for(int tgt=threadIdx.x; tgt<275; tgt+=256){
    if(tgt<253){
      int r=tgt, i=0;
      while(true){ int c=CIN_-i; if(r<c) break; r-=c; i++; }
      int j=i+r;
      const float4* ri=(const float4*)&xs[i][0];
      const float4* rj=(const float4*)&xs[j][0];
      float acc=0.f;
      for(int t=0;t<110;t++){
        float4 a=ri[t], bb=rj[t];
        acc += a.x*bb.x + a.y*bb.y + a.z*bb.z + a.w*bb.w;
      }
      atomicAdd(&ws[OFF_M + i*CIN_ + j], acc);
    } else {
      int c=tgt-253;
      const float4* rc=(const float4*)&xs[c][0];
      float acc=0.f;
      for(int t=0;t<110;t++){
        float4 a=rc[t];
        acc += a.x + a.y + a.z + a.w;
      }
      atomicAdd(&ws[OFF_S + c], acc);
    }
  }
}

// bn1 closed-form + fold conv1/bn1 into conv2: Weff[o][h][k], bias prefix pre[o][13]
__global__ __launch_bounds__(256) void k_prep(const float* __restrict__ w1, const float* __restrict__ cb1,
                                              const float* __restrict__ g1, const float* __restrict__ bb1,
                                              const float* __restrict__ w2, float* __restrict__ ws){
  __shared__ float a1s[CIN_], e1s[CIN_];
  int tid=threadIdx.x;
  if(tid<CIN_){
    int c=tid;
    const double N = (double)B_*T1_;
    double wS=0.0, wMw=0.0;
    for(int h=0;h<CIN_;h++) wS += (double)w1[c*CIN_+h]*(double)ws[OFF_S+h];
    for(int h=0;h<CIN_;h++){
      for(int h2=0;h2<CIN_;h2++){
        int i=h<h2?h:h2, j=h<h2?h2:h;
        wMw += (double)w1[c*CIN_+h]*(double)w1[c*CIN_+h2]*(double)ws[OFF_M+i*CIN_+j];
      }
    }
    double bc=cb1[c];
    double mean=wS/N+bc;
    double ex2=(wMw+2.0*bc*wS)/N+bc*bc;
    double var=ex2-mean*mean;
    double a1=(double)g1[c]/sqrt(var+1e-5);
    double d1=(double)bb1[c]-mean*a1;
    a1s[c]=(float)a1;
    e1s[c]=(float)(a1*bc+d1);
  }
  __syncthreads();
  for(int idx=tid; idx<5280; idx+=256){
    int o=idx/264, r=idx-o*264, h=r/12, k=r-h*12;
    float s=0.f;
    for(int i=0;i<CIN_;i++) s += w2[(o*CIN_+i)*12+k]*a1s[i]*w1[i*CIN_+h];
    ws[OFF_WEFF+idx]=s;
  }
  if(tid<COUT_){
    float pre=0.f;
    ws[OFF_BPRE+tid*13+0]=0.f;
    for(int k=0;k<12;k++){
      float wb=0.f;
      for(int i=0;i<CIN_;i++) wb += w2[(tid*CIN_+i)*12+k]*e1s[i];
      pre += wb;
      ws[OFF_BPRE+tid*13+k+1]=pre;
    }
  }
}

// direct conv x->h2 (folded kernel) + per-patch covariance + bn2 sums.
__global__ __launch_bounds__(256) void k_cov(const float* __restrict__ x,
                                             float* __restrict__ ws){
  __shared__ float Wl[5280];
  __shared__ float preL[COUT_][13];
  __shared__ float xs[CIN_][168];
  __shared__ float h2w[COUT_][156];
  __shared__ float pmu[COUT_];
  int b=blockIdx.x, tid=threadIdx.x;
  for(int i=tid;i<5280;i+=256) Wl[i]=ws[OFF_WEFF+i];
  for(int i=tid;i<260;i+=256) ((float*)preL)[i]=ws[OFF_BPRE+i];
  int pi=0,pj=0;
  if(tid<210){ int r=tid,i=0; while(true){int c=COUT_-i; if(r<c)break; r-=c; i++;} pi=i; pj=i+r; }
  int sc = tid-210;
  float ac1=0.f, ac2=0.f;
  const float* xb = x + (size_t)b*CIN_*T1_;
  int o = tid/12, cch = tid-12*o;
  int t0 = cch*13;
  for(int p=0;p<3;p++){
    const int off = (p==0)?0:((p==1)?147:293);
    const int L = (p==0)?147:146;
    __syncthreads();
    for(int idx=tid; idx<CIN_*168; idx+=256){
      int h=idx/168, c2=idx-h*168;
      int gxt = off-6+c2;
      xs[h][c2] = (c2<167 && gxt>=0 && gxt<T1_) ? xb[h*T1_+gxt] : 0.f;
    }
    __syncthreads();
    if(tid<240){
      float acc[13];
      #pragma unroll
      for(int j=0;j<13;j++){
        int gt = off+t0+j;
        int kmin = 6-gt; kmin = kmin<0?0:kmin;
        int kmax = 443-gt; kmax = kmax>11?11:kmax;
        acc[j] = (kmax>=kmin)? preL[o][kmax+1]-preL[o][kmin] : 0.f;
      }
      const float* Wo = &Wl[o*264];
      for(int h=0;h<CIN_;h++){
        float xw[24];
        #pragma unroll
        for(int c2=0;c2<24;c2++) xw[c2]=xs[h][t0+c2];
        const float* Wh = Wo + h*12;
        #pragma unroll
        for(int k=0;k<12;k++){
          float w=Wh[k];
          #pragma unroll
          for(int j=0;j<13;j++) acc[j] += w*xw[j+k];
        }
      }
      #pragma unroll
      for(int j=0;j<13;j++) if(t0+j<L) h2w[o][t0+j]=acc[j];
    } else {
      int npad = 156-L;
      for(int z=tid-240; z<COUT_*npad; z+=16){
        int oo=z/npad, c2=z-oo*npad;
        h2w[oo][L+c2]=0.f;
      }
    }
    __syncthreads();
    float s=0.f;
    if(tid<210){
      const float4* ri=(const float4*)&h2w[pi][0];
      const float4* rj=(const float4*)&h2w[pj][0];
      for(int t=0;t<39;t++){
        float4 a=ri[t], bb=rj[t];
        s += a.x*bb.x + a.y*bb.y + a.z*bb.z + a.w*bb.w;
      }
    } else if(sc>=0 && sc<COUT_){
      const float4* rc=(const float4*)&h2w[sc][0];
      float s1=0.f,s2=0.f;
      for(int t=0;t<39;t++){
        float4 a=rc[t];
        s1 += a.x+a.y+a.z+a.w;
        s2 += a.x*a.x+a.y*a.y+a.z*a.z+a.w*a.w;
      }
      ac1+=s1; ac2+=s2; pmu[sc]=s1/(float)L;
    }
    __syncthreads();
    if(tid<210){
      s -= (float)L*pmu[pi]*pmu[pj];
      float* Cb = ws + OFF_C + ((size_t)b*3+p)*400;
      Cb[pi*COUT_+pj]=s; Cb[pj*COUT_+pi]=s;
    }
  }
  if(sc>=0 && sc<COUT_){
    atomicAdd(&ws[OFF_SUM2+sc], ac1);
    atomicAdd(&ws[OFF_SSQ2+sc], ac2);
  }
}

__global__ void k_fin2(const float* __restrict__ g2, float* __restrict__ ws){
  int c=threadIdx.x; if(c>=COUT_) return;
  const double N=(double)B_*T2_;
  double m=ws[OFF_SUM2+c]/N;
  double v=ws[OFF_SSQ2+c]/N - m*m;
  ws[OFF_A2+c]=(float)((double)g2[c]/sqrt(v+1e-5));
}

// ---------------------------------------------------------------------------
// Brent-Luk one-sided Jacobi, columns-in-lanes, BATCHED-SHUFFLE version.
// 9 lanes per matrix; 7 matrices per wave in k_eighQKV (63/64 lanes).
// The rotate+migrate is split into phases so all 36 ds_bpermutes per round are
// independent and pipeline (R6-R8's fused loop serialized on per-iteration
// lgkmcnt waits -> ~3000 cyc/round; target ~400).
// ---------------------------------------------------------------------------
__device__ __forceinline__ void bl_jacobi(float P[18], float Q[18],
                                          float &dgp, float &dgq,
                                          int l9, int srcP, int srcQ, int maxsweep){
  for(int sweep=0; sweep<maxsweep; sweep++){
    float n0=0.f,n1=0.f,m0=0.f,m1=0.f;
    #pragma unroll
    for(int k=0;k<18;k+=2){
      n0 += P[k]*P[k];   n1 += P[k+1]*P[k+1];
      m0 += Q[k]*Q[k];   m1 += Q[k+1]*Q[k+1];
    }
    dgp = n0+n1; dgq = m0+m1;
    float smax = 0.f;
    for(int r=0;r<17;r++){
      float a0=0.f,a1=0.f;
      #pragma unroll
      for(int k=0;k<18;k+=2){ a0 += P[k]*Q[k]; a1 += P[k+1]*Q[k+1]; }
      float apq = a0+a1;
      float tau = __fdividef(dgq-dgp, 2.f*apq);
      float tt  = __fdividef(copysignf(1.f,tau), fabsf(tau)+sqrtf(1.f+tau*tau));
      float c   = rsqrtf(1.f+tt*tt);
      float s   = tt*c;
      bool  z   = (apq==0.f);
      tt = z?0.f:tt; c = z?1.f:c; s = z?0.f:s;
      float ndgp = dgp - tt*apq;
      float ndgq = dgq + tt*apq;
      smax = fmaxf(smax, fabsf(s));
      // phase 1: rotate (pure VALU, independent)
      float rp[18], rq[18], np[18], nq[18];
      #pragma unroll
      for(int k=0;k<18;k++){
        float x=P[k], y=Q[k];
        rp[k] = c*x - s*y;
        rq[k] = s*x + c*y;
      }
      // phase 2: all srcP pulls (18 independent bpermutes)
      #pragma unroll
      for(int k=0;k<18;k++) np[k] = __shfl(rp[k], srcP);
      // phase 3: all srcQ pulls (18 independent bpermutes)
      #pragma unroll
      for(int k=0;k<18;k++){
        float sq = (l9==0) ? rp[k] : rq[k];
        nq[k] = __shfl(sq, srcQ);
      }
      // phase 4: selects
      #pragma unroll
      for(int k=0;k<18;k++){
        P[k] = (l9==8) ? rq[k] : np[k];
        Q[k] = (l9==0) ? rq[k] : nq[k];
      }
      // dg travels with its column
      {
        float npd = __shfl(ndgp, srcP);
        float sqd = (l9==0) ? ndgp : ndgq;
        float nqd = __shfl(sqd, srcQ);
        dgp = (l9==8) ? ndgq : npd;
        dgq = (l9==0) ? ndgq : nqd;
      }
    }
    if(__all(smax < 3e-3f)) break;
  }
  float n0=0.f,n1=0.f,m0=0.f,m1=0.f;
  #pragma unroll
  for(int k=0;k<18;k+=2){
    n0 += P[k]*P[k];   n1 += P[k+1]*P[k+1];
    m0 += Q[k]*Q[k];   m1 += Q[k+1]*Q[k+1];
  }
  dgp = n0+n1; dgq = m0+m1;
}

// 7 matrices per 1-wave block (63 active lanes). Prep folds: Wa=W*a2 once per
// block; 1/tr and +1e-5I folded into spectral weights (W has orthonormal cols).
// Mc stride 21 (coprime 32) to kill output-phase bank conflicts.
__global__ __launch_bounds__(64) void k_eighQKV(const float* __restrict__ Wq,
                                                const float* __restrict__ Wk,
                                                const float* __restrict__ Wv,
                                                float* __restrict__ ws){
  __shared__ float S[4990];
  float* Wa  = S;          // 1080 (3x360, a2-folded)
  float* a2s = S+1080;     // 20
  float* Cs  = S+1100;     // 400 raw C
  float* Tt  = S+1500;     // 378 (18x21)
  float* Af  = S+1878;     // 324
  float* trs = S+2202;     // 8
  float* Mc  = S+2210;     // 7 x 378 (rows stride 21)
  float* gl  = S+4856;     // 126
  int blk=blockIdx.x, tid=threadIdx.x;
  int g=tid/9, l9=tid-9*g;                       // g==7 -> lane 63 idle
  int srcP=min(g*9+((l9==8)?8:(l9+1)),63);
  int srcQ=g*9+((l9==0)?0:(l9-1));
  int ps=l9, qs=(l9==0)?17:(17-l9);

  if(tid<20) a2s[tid]=ws[OFF_A2+tid];
  __syncthreads();
  for(int i=tid;i<1080;i+=64){
    int m=i/360, r=i-m*360, row=r/18;
    const float* W=(m==0)?Wq:((m==1)?Wk:Wv);
    Wa[i]=W[r]*a2s[row];
  }
  __syncthreads();

  float P[18],Q[18],dgp,dgq;
  #pragma unroll
  for(int k=0;k<18;k++){ P[k]=0.f; Q[k]=0.f; }

  for(int gp_=0; gp_<7; gp_++){
    int id=min(blk*7+gp_,9215);
    int m=id/3072, bp=id-m*3072;
    const float* Cb=ws+OFF_C+(size_t)bp*400;
    for(int i=tid;i<400;i+=64) Cs[i]=Cb[i];
    __syncthreads();
    if(tid==63){
      float tr=0.f;
      #pragma unroll
      for(int i=0;i<20;i++) tr += Cs[i*20+i]*a2s[i]*a2s[i];
      trs[gp_]=tr;
    }
    const float* Wm=Wa+m*360;
    for(int idx=tid; idx<360; idx+=64){
      int a=idx/20, j=idx-a*20;
      float s=0.f;
      for(int i=0;i<20;i++) s += Wm[i*18+a]*Cs[i*20+j];
      Tt[a*21+j]=s;
    }
    __syncthreads();
    for(int idx=tid; idx<324; idx+=64){
      int a=idx/18, c=idx-a*18;
      float s=0.f;
      for(int j=0;j<20;j++) s += Tt[a*21+j]*Wm[j*18+c];
      Af[idx]=s;
    }
    __syncthreads();
    if(g==gp_){
      float sh=1e-5f*trs[gp_];
      #pragma unroll
      for(int k=0;k<18;k++){
        P[k]=0.5f*(Af[k*18+ps]+Af[ps*18+k]) + ((k==ps)?sh:0.f);
        Q[k]=0.5f*(Af[k*18+qs]+Af[qs*18+k]) + ((k==qs)?sh:0.f);
      }
    }
    __syncthreads();
  }

  bl_jacobi(P,Q,dgp,dgq,l9,srcP,srcQ,8);

  // lambda_true = sqrt(dg)/tr; g_k = (0.5*log(dg) - log(tr))/dg
  float logtr = (g<7) ? logf(trs[g]) : 0.f;
  float dp=fmaxf(dgp,1e-30f), dq=fmaxf(dgq,1e-30f);
  float gpv=__fdividef(0.5f*logf(dp)-logtr, dp);
  float gqv=__fdividef(0.5f*logf(dq)-logtr, dq);
  if(g<7){
    #pragma unroll
    for(int k=0;k<18;k++){
      Mc[g*378 + k*21 + ps]=P[k];
      Mc[g*378 + k*21 + qs]=Q[k];
    }
    gl[g*18+ps]=gpv; gl[g*18+qs]=gqv;
  }
  __syncthreads();
  // out[i][j] = sum_k gl[k]*Mc[i][k]*Mc[j][k]
  for(int idx=tid; idx<126; idx+=64){
    int mat=idx/18, i=idx-mat*18;
    int id=blk*7+mat;
    if(id<9216){
      int m=id/3072, bp=id-m*3072;
      float w[18];
      #pragma unroll
      for(int k=0;k<18;k++) w[k]=gl[mat*18+k]*Mc[mat*378+i*21+k];
      float* ob=ws+((m==0)?OFF_LQ:((m==1)?OFF_LK:OFF_LV))+(size_t)bp*324+i*18;
      for(int j=0;j<18;j++){
        float s=0.f;
        #pragma unroll
        for(int k=0;k<18;k++) s += w[k]*Mc[mat*378+j*21+k];
        ob[j]=s;
      }
    }
  }
}

// fused: energies + softmax + mean_log + eigh(+12I) + triu feat + LINEAR out
__global__ __launch_bounds__(64) void k_att2(const float* __restrict__ lw,
                                             const float* __restrict__ lb,
                                             float* __restrict__ ws,
                                             float* __restrict__ out){
  __shared__ float lv[972];     // aliased as feat (513) after ml computed
  __shared__ float lqk[1944];   // lq | lk ; reused as ml after softmax
  __shared__ float e9[9];
  __shared__ float prob[9];
  __shared__ float Mc[1080];
  __shared__ float gl[54];
  int b=blockIdx.x, tid=threadIdx.x;
  const float4* LQ4=(const float4*)(ws+OFF_LQ+(size_t)b*972);
  const float4* LK4=(const float4*)(ws+OFF_LK+(size_t)b*972);
  const float4* LV4=(const float4*)(ws+OFF_LV+(size_t)b*972);
  float4* lqk4=(float4*)lqk; float4* lv4=(float4*)lv;
  for(int i=tid;i<243;i+=64){ lqk4[i]=LQ4[i]; lqk4[243+i]=LK4[i]; lv4[i]=LV4[i]; }
  __syncthreads();
  if(tid<36){
    int d=tid>>2, sub=tid&3;
    int ii=d/3, p=d-ii*3;
    const float* kk=lqk+972+ii*324+sub*81;
    const float* qq=lqk+p*324+sub*81;
    float s=0.f;
    for(int el=0;el<81;el++){ float dd=kk[el]-qq[el]; s+=dd*dd; }
    s += __shfl_xor(s,1); s += __shfl_xor(s,2);
    if(sub==0) e9[d]=s;
  }
  __syncthreads();
  if(tid<3){
    int p=tid;
    float f0=1.f/(1.f+log1pf(e9[0+p]));
    float f1=1.f/(1.f+log1pf(e9[3+p]));
    float f2=1.f/(1.f+log1pf(e9[6+p]));
    float mx=fmaxf(f0,fmaxf(f1,f2));
    float x0=expf(f0-mx), x1=expf(f1-mx), x2=expf(f2-mx);
    float inv=1.f/(x0+x1+x2);
    prob[p*3+0]=x0*inv; prob[p*3+1]=x1*inv; prob[p*3+2]=x2*inv;
  }
  __syncthreads();
  float* ml = lqk;
  for(int idx=tid; idx<972; idx+=64){
    int p=idx/324, el=idx-p*324;
    ml[idx]=prob[p*3+0]*lv[el]+prob[p*3+1]*lv[324+el]+prob[p*3+2]*lv[648+el];
  }
  __syncthreads();
  int g=tid/9, l9=tid-9*g;
  int srcP=min(g*9+((l9==8)?8:(l9+1)),63);
  int srcQ=g*9+((l9==0)?0:(l9-1));
  int ps=l9, qs=(l9==0)?17:(17-l9);
  float P[18],Q[18],dgp,dgq;
  if(g<3){
    const float* Ag=ml+g*324;
    #pragma unroll
    for(int k=0;k<18;k++){
      P[k]=0.5f*(Ag[k*18+ps]+Ag[ps*18+k]) + ((k==ps)?12.f:0.f);
      Q[k]=0.5f*(Ag[k*18+qs]+Ag[qs*18+k]) + ((k==qs)?12.f:0.f);
    }
  } else {
    #pragma unroll
    for(int k=0;k<18;k++){ P[k]=0.f; Q[k]=0.f; }
  }
  __syncthreads();
  bl_jacobi(P,Q,dgp,dgq,l9,srcP,srcQ,8);
  float lp=sqrtf(dgp), lqv=sqrtf(dgq);
  float gpv=__fdividef(fmaxf(lp-12.f,-9.2103404f), fmaxf(dgp,1e-12f));
  float gqv=__fdividef(fmaxf(lqv-12.f,-9.2103404f), fmaxf(dgq,1e-12f));
  if(g<3){
    #pragma unroll
    for(int k=0;k<18;k++){
      Mc[g*360 + k*20 + ps]=P[k];
      Mc[g*360 + k*20 + qs]=Q[k];
    }
    gl[g*18+ps]=gpv; gl[g*18+qs]=gqv;
  }
  __syncthreads();
  float* feat = lv;
  if(tid<54){
    int mat=tid/18, i=tid-mat*18;
    float w[18];
    #pragma unroll
    for(int k=0;k<18;k++) w[k]=gl[mat*18+k]*Mc[mat*360+i*20+k];
    int base = mat*171 + (i*18 - (i*(i-1))/2) - i;
    for(int j=i;j<18;j++){
      float s=0.f;
      #pragma unroll
      for(int k=0;k<18;k++) s += w[k]*Mc[mat*360+j*20+k];
      feat[base+j]=s;
    }
  }
  __syncthreads();
  int j4 = tid&3, chunk = tid>>2;
  float s=0.f;
  const float* wj = lw + j4*513;
  for(int k=chunk; k<513; k+=16) s += feat[k]*wj[k];
  s += __shfl_xor(s,4); s += __shfl_xor(s,8);
  s += __shfl_xor(s,16); s += __shfl_xor(s,32);
  if(chunk==0) out[b*4+j4] = s + lb[j4];
}

extern "C" void kernel_launch(void* const* d_in, const int* in_sizes, int n_in,
                              void* d_out, int out_size, void* d_ws, size_t ws_size,
                              hipStream_t stream){
  const float* x  =(const float*)d_in[0];
  const float* w1 =(const float*)d_in[1];
  const float* cb1=(const float*)d_in[2];
  const float* g1 =(const float*)d_in[3];
  const float* bb1=(const float*)d_in[4];
  const float* w2 =(const float*)d_in[5];
  // d_in[6] conv2_b, d_in[8] bn2_b: provably cancel
  const float* g2 =(const float*)d_in[7];
  const float* Wq =(const float*)d_in[9];
  const float* Wk =(const float*)d_in[10];
  const float* Wv =(const float*)d_in[11];
  const float* lw =(const float*)d_in[12];
  const float* lb =(const float*)d_in[13];
  float* ws=(float*)d_ws;
  float* out=(float*)d_out;

  k_zero<<<1,256,0,stream>>>(ws);
  k_moment<<<B_,256,0,stream>>>(x,ws);
  k_prep<<<1,256,0,stream>>>(w1,cb1,g1,bb1,w2,ws);
  k_cov<<<B_,256,0,stream>>>(x,ws);
  k_fin2<<<1,64,0,stream>>>(g2,ws);
  k_eighQKV<<<1317,64,0,stream>>>(Wq,Wk,Wv,ws);   // 7 matrices per wave
  k_att2<<<B_,64,0,stream>>>(lw,lb,ws,out);       // fused att+eigh2+feat+linear
}